// Round 1
// baseline (449.121 us; speedup 1.0000x reference)
//
#include <hip/hip_runtime.h>

#define NUM_CLASSES 19
#define IGNORE_INDEX (-1)
#define BATCH 8
#define HW (512 * 1024)            // pixels per image, 2^19
#define NPIX (BATCH * HW)          // 4,194,304
#define NGROUP (NPIX / 4)          // 1,048,576 float4 groups
#define NBINS (3 * NUM_CLASSES)    // label | pred | intersect

// Histogram kernel: one thread handles 4 consecutive pixels (float4/int4 loads).
// Per-wave LDS sub-histograms -> block reduce -> global atomics into d_ws.
__global__ __launch_bounds__(256) void iou_hist_kernel(
    const float* __restrict__ pred,
    const int* __restrict__ label,
    unsigned int* __restrict__ ghist)
{
    __shared__ unsigned int h[4][NBINS];  // one sub-histogram per wave
    const int tid = threadIdx.x;
    const int wid = tid >> 6;             // wave id within block (wave64)

    for (int i = tid; i < 4 * NBINS; i += 256) ((unsigned int*)h)[i] = 0u;
    __syncthreads();

    unsigned int* __restrict__ hw_ = h[wid];

    const int stride = gridDim.x * 256;
    for (int g = blockIdx.x * 256 + tid; g < NGROUP; g += stride) {
        const int p  = g << 2;                 // first pixel of group
        const int b  = p >> 19;                // p / HW
        const int hw = p & (HW - 1);           // p % HW

        const float* bp = pred + (long)b * (long)(NUM_CLASSES * (long)HW) + hw;
        float4 best = *(const float4*)bp;
        int bcx = 0, bcy = 0, bcz = 0, bcw = 0;
#pragma unroll
        for (int c = 1; c < NUM_CLASSES; ++c) {
            bp += HW;
            const float4 v = *(const float4*)bp;
            if (v.x > best.x) { best.x = v.x; bcx = c; }
            if (v.y > best.y) { best.y = v.y; bcy = c; }
            if (v.z > best.z) { best.z = v.z; bcz = c; }
            if (v.w > best.w) { best.w = v.w; bcw = c; }
        }

        const int4 lab = ((const int4*)label)[g];

        // per-pixel histogram updates
        {
            const int l = lab.x;
            if (l != IGNORE_INDEX) {
                const int lc = min(max(l, 0), NUM_CLASSES - 1);
                atomicAdd(&hw_[lc], 1u);
                atomicAdd(&hw_[NUM_CLASSES + bcx], 1u);
                if (bcx == l) atomicAdd(&hw_[2 * NUM_CLASSES + lc], 1u);
            }
        }
        {
            const int l = lab.y;
            if (l != IGNORE_INDEX) {
                const int lc = min(max(l, 0), NUM_CLASSES - 1);
                atomicAdd(&hw_[lc], 1u);
                atomicAdd(&hw_[NUM_CLASSES + bcy], 1u);
                if (bcy == l) atomicAdd(&hw_[2 * NUM_CLASSES + lc], 1u);
            }
        }
        {
            const int l = lab.z;
            if (l != IGNORE_INDEX) {
                const int lc = min(max(l, 0), NUM_CLASSES - 1);
                atomicAdd(&hw_[lc], 1u);
                atomicAdd(&hw_[NUM_CLASSES + bcz], 1u);
                if (bcz == l) atomicAdd(&hw_[2 * NUM_CLASSES + lc], 1u);
            }
        }
        {
            const int l = lab.w;
            if (l != IGNORE_INDEX) {
                const int lc = min(max(l, 0), NUM_CLASSES - 1);
                atomicAdd(&hw_[lc], 1u);
                atomicAdd(&hw_[NUM_CLASSES + bcw], 1u);
                if (bcw == l) atomicAdd(&hw_[2 * NUM_CLASSES + lc], 1u);
            }
        }
    }

    __syncthreads();
    for (int i = tid; i < NBINS; i += 256) {
        const unsigned int s = h[0][i] + h[1][i] + h[2][i] + h[3][i];
        if (s) atomicAdd(&ghist[i], s);
    }
}

// Final scalar: 1 - nanmean(inter/union); all-NaN -> 0.5 (matches reference).
__global__ void iou_finish_kernel(const unsigned int* __restrict__ ghist,
                                  float* __restrict__ out)
{
    if (threadIdx.x == 0 && blockIdx.x == 0) {
        float sum = 0.0f;
        int cnt = 0;
        for (int c = 0; c < NUM_CLASSES; ++c) {
            const float a_lab = (float)ghist[c];
            const float a_prd = (float)ghist[NUM_CLASSES + c];
            const float a_int = (float)ghist[2 * NUM_CLASSES + c];
            const float a_uni = a_prd + a_lab - a_int;
            if (a_uni > 0.0f) { sum += a_int / a_uni; ++cnt; }
            // a_uni == 0 -> 0/0 -> NaN -> skipped by nanmean
        }
        const float mean = (cnt > 0) ? (sum / (float)cnt) : 0.5f;
        out[0] = 1.0f - mean;
    }
}

extern "C" void kernel_launch(void* const* d_in, const int* in_sizes, int n_in,
                              void* d_out, int out_size, void* d_ws, size_t ws_size,
                              hipStream_t stream)
{
    const float* pred  = (const float*)d_in[0];
    const int*   label = (const int*)d_in[1];
    float*       out   = (float*)d_out;
    unsigned int* ghist = (unsigned int*)d_ws;

    // d_ws is poisoned 0xAA before every launch — zero the histogram bins.
    hipMemsetAsync(ghist, 0, NBINS * sizeof(unsigned int), stream);

    // 1024 blocks x 256 threads = 262,144 threads; 4 groups (16 pixels) each.
    iou_hist_kernel<<<1024, 256, 0, stream>>>(pred, label, ghist);
    iou_finish_kernel<<<1, 64, 0, stream>>>(ghist, out);
}